// Round 13
// baseline (291.569 us; speedup 1.0000x reference)
//
#include <hip/hip_runtime.h>
#include <hip/hip_fp16.h>
#include <math.h>

// GAT 3-layer net, v13.
//  - v12 (279us): bucket-sort CSR fixed write-amp; k_agg2f now top kernel
//    (55.8us, VALUBusy 73% = VALU-throughput-bound).
//  - v13: phase-B cross-lane broadcast via __shfl with LANE-VARYING index
//    (jk + (half<<5), one ds_bpermute) instead of 4x readlane + 2x cndmask
//    -> ~12 -> ~8 VALU/edge in the dominant loop. No other changes.

#define NEG_BIG (-1e30f)
#define SORT_CAP 6144
#define CHUNK 8192

__device__ inline float waveSum(float v) {
#pragma unroll
  for (int off = 32; off; off >>= 1) v += __shfl_xor(v, off, 64);
  return v;
}

__device__ inline float halfSum(float v) {
#pragma unroll
  for (int off = 16; off; off >>= 1) v += __shfl_xor(v, off, 64);
  return v;
}

__device__ inline float halfMax(float v) {
#pragma unroll
  for (int off = 16; off; off >>= 1) v = fmaxf(v, __shfl_xor(v, off, 64));
  return v;
}

__device__ inline int waveMaxI(int v) {
#pragma unroll
  for (int off = 32; off; off >>= 1) v = max(v, __shfl_xor(v, off, 64));
  return v;
}

__device__ inline float rlF(float v, int l) {
  return __int_as_float(__builtin_amdgcn_readlane(__float_as_int(v), l));
}
__device__ inline int ntI(const int* p) { return __builtin_nontemporal_load(p); }

// ---------- bucket binning: LDS-chunked histogram ----------
__global__ __launch_bounds__(256) void k_hist(const int* __restrict__ dst,
                                              int* __restrict__ gcount,
                                              int E, int NBK) {
  __shared__ int lcnt[512];
  int tid = threadIdx.x;
  for (int b = tid; b < NBK; b += 256) lcnt[b] = 0;
  __syncthreads();
  int e0 = blockIdx.x * CHUNK;
  int e1 = min(e0 + CHUNK, E);
  for (int e = e0 + tid; e < e1; e += 256)
    atomicAdd(&lcnt[ntI(&dst[e]) >> 8], 1);
  __syncthreads();
  for (int b = tid; b < NBK; b += 256)
    if (lcnt[b]) atomicAdd(&gcount[b], lcnt[b]);
}

// single block: exclusive scan of gcount[NBK] -> base, cursor
__global__ void k_bscan(const int* __restrict__ cnt, int* __restrict__ base,
                        int* __restrict__ cursor, int NBK, int E,
                        int* __restrict__ startv, int N) {
  __shared__ int s[1024];
  int t = threadIdx.x;
  int v = (t < NBK) ? cnt[t] : 0;
  s[t] = v;
  __syncthreads();
  for (int off = 1; off < 1024; off <<= 1) {
    int u = (t >= off) ? s[t - off] : 0;
    __syncthreads();
    s[t] += u;
    __syncthreads();
  }
  int excl = s[t] - v;
  if (t < NBK) { base[t] = excl; cursor[t] = excl; }
  if (t == NBK) base[t] = excl;         // == E
  if (t == 0) startv[N] = E;
}

// block-chunked bin: reserve contiguous ranges, write runs
__global__ __launch_bounds__(256) void k_bin2(
    const int* __restrict__ src, const int* __restrict__ dst,
    int* __restrict__ gcursor, unsigned* __restrict__ binned, int E, int NBK) {
  __shared__ int lcnt[512];
  __shared__ int lbase[512];
  int tid = threadIdx.x;
  for (int b = tid; b < NBK; b += 256) lcnt[b] = 0;
  __syncthreads();
  int e0 = blockIdx.x * CHUNK;
  int e1 = min(e0 + CHUNK, E);
  for (int e = e0 + tid; e < e1; e += 256)
    atomicAdd(&lcnt[ntI(&dst[e]) >> 8], 1);
  __syncthreads();
  for (int b = tid; b < NBK; b += 256) {
    int c = lcnt[b];
    lbase[b] = c ? atomicAdd(&gcursor[b], c) : 0;
    lcnt[b] = 0;
  }
  __syncthreads();
  for (int e = e0 + tid; e < e1; e += 256) {
    int dd = ntI(&dst[e]);
    int ss = ntI(&src[e]);
    int b = dd >> 8;
    int pos = lbase[b] + atomicAdd(&lcnt[b], 1);
    binned[pos] = ((unsigned)(dd & 255) << 24) | (unsigned)ss;
  }
}

// one block per bucket: per-dst order within bucket, coalesced csr write
__global__ __launch_bounds__(256) void k_sort(
    const unsigned* __restrict__ binned, const int* __restrict__ base,
    int* __restrict__ csr, int* __restrict__ startv, int N) {
  __shared__ unsigned sbuf[SORT_CAP];
  __shared__ unsigned obuf[SORT_CAP];
  __shared__ int hist[256];
  __shared__ int scn[256];
  __shared__ int cur[256];
  int b = blockIdx.x;
  int tid = threadIdx.x;
  int gbase = base[b];
  int gend = base[b + 1];
  int cnt = gend - gbase;
  hist[tid] = 0;
  __syncthreads();
  if (cnt <= SORT_CAP) {
    for (int i = tid; i < cnt; i += 256) {
      unsigned w = binned[gbase + i];
      sbuf[i] = w;
      atomicAdd(&hist[w >> 24], 1);
    }
    __syncthreads();
    int v = hist[tid];
    scn[tid] = v;
    __syncthreads();
    for (int off = 1; off < 256; off <<= 1) {
      int u = (tid >= off) ? scn[tid - off] : 0;
      __syncthreads();
      scn[tid] += u;
      __syncthreads();
    }
    int excl = scn[tid] - v;
    cur[tid] = excl;
    int dn = b * 256 + tid;
    if (dn < N) startv[dn] = gbase + excl;
    __syncthreads();
    for (int i = tid; i < cnt; i += 256) {
      unsigned w = sbuf[i];
      int p = atomicAdd(&cur[w >> 24], 1);
      obuf[p] = w & 0xFFFFFFu;
    }
    __syncthreads();
    for (int i = tid; i < cnt; i += 256) csr[gbase + i] = (int)obuf[i];
  } else {
    for (int i = tid; i < cnt; i += 256)
      atomicAdd(&hist[binned[gbase + i] >> 24], 1);
    __syncthreads();
    int v = hist[tid];
    scn[tid] = v;
    __syncthreads();
    for (int off = 1; off < 256; off <<= 1) {
      int u = (tid >= off) ? scn[tid - off] : 0;
      __syncthreads();
      scn[tid] += u;
      __syncthreads();
    }
    int excl = scn[tid] - v;
    cur[tid] = excl;
    int dn = b * 256 + tid;
    if (dn < N) startv[dn] = gbase + excl;
    __syncthreads();
    for (int i = tid; i < cnt; i += 256) {
      unsigned w = binned[gbase + i];
      int p = atomicAdd(&cur[w >> 24], 1);
      csr[gbase + p] = (int)(w & 0xFFFFFFu);
    }
  }
}

// ---------- prep: uvw[0..5]=W1@al1|W1@ar1; [8..71]=W2@al2; [72..135]=W2@ar2
__global__ void k_prep(const float* __restrict__ W1, const float* __restrict__ al1,
                       const float* __restrict__ ar1, const float* __restrict__ W2,
                       const float* __restrict__ al2, const float* __restrict__ ar2,
                       float* __restrict__ uvw) {
  int lane = threadIdx.x & 63;
  float a = al1[lane], r = ar1[lane];
#pragma unroll
  for (int i = 0; i < 3; ++i) {
    float w = W1[i * 64 + lane];
    float ui = waveSum(w * a);
    float vi = waveSum(w * r);
    if (lane == 0) { uvw[i] = ui; uvw[3 + i] = vi; }
  }
  float sa = 0.f, sr = 0.f;
  for (int j = 0; j < 64; ++j) {
    float w = W2[lane * 64 + j];
    sa = fmaf(w, al2[j], sa);
    sr = fmaf(w, ar2[j], sr);
  }
  uvw[8 + lane] = sa;
  uvw[72 + lane] = sr;
}

// ---------- pad x + per-node layer-1 logits: x4=(x, u·x), er1=v·x ----------
__global__ void k_padx(const float* __restrict__ x, const float* __restrict__ uvw,
                       float4* __restrict__ x4, float* __restrict__ er1, int N) {
  int n = blockIdx.x * blockDim.x + threadIdx.x;
  if (n >= N) return;
  float x0 = __builtin_nontemporal_load(&x[n * 3]);
  float x1 = __builtin_nontemporal_load(&x[n * 3 + 1]);
  float x2 = __builtin_nontemporal_load(&x[n * 3 + 2]);
  float el = fmaf(x0, uvw[0], fmaf(x1, uvw[1], x2 * uvw[2]));
  float er = fmaf(x0, uvw[3], fmaf(x1, uvw[4], x2 * uvw[5]));
  x4[n] = make_float4(x0, x1, x2, el);
  er1[n] = er;
}

// ---------- layer-1: x-space agg (2 nodes/wave) -> x2 fp16, el2/er2 --------
__global__ __launch_bounds__(256) void k_agg1x(
    const float4* __restrict__ x4, const float* __restrict__ er1,
    const float* __restrict__ uvw, const float* __restrict__ W1,
    const float* __restrict__ b1, const int* __restrict__ start,
    const int* __restrict__ csr, __half* __restrict__ x2,
    float* __restrict__ el2, float* __restrict__ er2, int N) {
  int tid = threadIdx.x;
  int wave = tid >> 6, lane = tid & 63, hl = lane & 31, half = lane >> 5;
  int pA = blockIdx.x * 8 + wave * 2;
  int pn = pA + half;
  int n = (pn < N) ? pn : 0;
  int beg = start[n], end = start[n + 1];
  float ern = er1[n];
  float m = NEG_BIG, d = 0.f, X0 = 0.f, X1 = 0.f, X2 = 0.f;
  for (int base = beg; base < end; base += 32) {
    int idx = base + hl;
    int s = (idx < end) ? ntI(&csr[idx]) : 0;
    s = ((unsigned)s < (unsigned)N) ? s : 0;
    float4 hv = x4[s];
    float e = hv.w + ern;
    e = e > 0.f ? e : 0.2f * e;             // attn leaky_relu(0.2)
    e = (idx < end) ? e : NEG_BIG;
    float mn = fmaxf(m, halfMax(e));
    float sc = __expf(m - mn);
    float q = __expf(e - mn);
    d = d * sc + halfSum(q);
    X0 = X0 * sc + halfSum(q * hv.x);
    X1 = X1 * sc + halfSum(q * hv.y);
    X2 = X2 * sc + halfSum(q * hv.z);
    m = mn;
  }
  float inv = (end > beg) ? 1.f / d : 0.f;
  X0 *= inv; X1 *= inv; X2 *= inv;
  float A0 = rlF(X0, 0), A1 = rlF(X1, 0), A2 = rlF(X2, 0);
  float B0 = rlF(X0, 32), B1 = rlF(X1, 32), B2 = rlF(X2, 32);
  float w1a = W1[lane], w1b = W1[64 + lane], w1c = W1[128 + lane];
  float bb = b1[lane];
  float wal = uvw[8 + lane], war = uvw[72 + lane];
  {
    float vA = fmaf(A0, w1a, fmaf(A1, w1b, fmaf(A2, w1c, bb)));
    vA = vA > 0.f ? vA : 0.01f * vA;        // leaky_relu(0.01)
    float eA = waveSum(vA * wal);
    float rA = waveSum(vA * war);
    if (pA < N) {
      x2[(size_t)pA * 64 + lane] = __float2half(vA);
      if (lane == 0) { el2[pA] = eA; er2[pA] = rA; }
    }
  }
  {
    int pB = pA + 1;
    float vB = fmaf(B0, w1a, fmaf(B1, w1b, fmaf(B2, w1c, bb)));
    vB = vB > 0.f ? vB : 0.01f * vB;
    float eB = waveSum(vB * wal);
    float rB = waveSum(vB * war);
    if (pB < N) {
      x2[(size_t)pB * 64 + lane] = __float2half(vB);
      if (lane == 0) { el2[pB] = eB; er2[pB] = rB; }
    }
  }
}

// ---------- batched GEMM: h2 = x2 @ W2, in-place ----------
__global__ __launch_bounds__(256) void k_gemm2(const __half* x2_in,
                                               const float* __restrict__ W2,
                                               __half* h2_out, int N) {
  __shared__ float sW[64 * 64];
  __shared__ float sX[64 * 64];
  int tid = threadIdx.x;
  for (int i = tid; i < 4096; i += 256) sW[i] = W2[i];
  const unsigned* xu = (const unsigned*)x2_in;
  size_t base = (size_t)blockIdx.x * 2048;
  size_t limit = (size_t)N * 32;
  for (int i = tid; i < 2048; i += 256) {
    size_t gi = base + i;
    unsigned u = (gi < limit) ? __builtin_nontemporal_load(&xu[gi]) : 0u;
    __half2 hh = *(__half2*)&u;
    float2 f = __half22float2(hh);
    sX[2 * i] = f.x;
    sX[2 * i + 1] = f.y;
  }
  __syncthreads();
  int wave = tid >> 6, f = tid & 63;
  int r0 = wave * 16;
  float acc[16];
#pragma unroll
  for (int i = 0; i < 16; ++i) acc[i] = 0.f;
  const float2* sX2 = (const float2*)sX;
  for (int k2 = 0; k2 < 32; ++k2) {
    float wv0 = sW[(2 * k2) * 64 + f];
    float wv1 = sW[(2 * k2 + 1) * 64 + f];
#pragma unroll
    for (int i = 0; i < 16; ++i) {
      float2 xv = sX2[(r0 + i) * 32 + k2];
      acc[i] = fmaf(xv.x, wv0, fmaf(xv.y, wv1, acc[i]));
    }
  }
  int rowbase = blockIdx.x * 64 + r0;
#pragma unroll
  for (int i = 0; i < 16; ++i) {
    int row = rowbase + i;
    if (row < N) h2_out[(size_t)row * 64 + f] = __float2half(acc[i]);
  }
}

// ---------- layer-2 aggregate (2 nodes/wave) + fused W3 -> h3 (w=el3) ------
__global__ __launch_bounds__(256) void k_agg2f(
    const __half* __restrict__ h2, const float* __restrict__ el,
    const float* __restrict__ er, const int* __restrict__ start,
    const int* __restrict__ csr, const float* __restrict__ b2,
    const float* __restrict__ W3, const float* __restrict__ al3,
    float* __restrict__ h3, int N) {
  int tid = threadIdx.x;
  int wave = tid >> 6, lane = tid & 63, hl = lane & 31, half = lane >> 5;
  int pn = blockIdx.x * 8 + wave * 2 + half;
  int n = (pn < N) ? pn : 0;
  int beg = start[n], end = start[n + 1];
  int deg = end - beg;
  int maxd = __builtin_amdgcn_readfirstlane(waveMaxI(deg));
  float ern = er[n];
  float ox = 0.f, oy = 0.f;
  int hbase = half << 5;                   // lane-varying shfl base

  if (maxd <= 32) {
    int idx = beg + hl;
    int s = (idx < end) ? ntI(&csr[idx]) : 0;
    s = ((unsigned)s < (unsigned)N) ? s : 0;
    float e = el[s] + ern;
    e = e > 0.f ? e : 0.2f * e;
    e = (idx < end) ? e : NEG_BIG;
    float mm = halfMax(e);
    float q = __expf(e - mm);
    float dsum = halfSum(q);
    float inv = (deg > 0) ? 1.f / dsum : 0.f;
    float a = q * inv;                      // 0 for invalid lanes
    for (int j = 0; j < maxd; j += 4) {
#pragma unroll
      for (int k = 0; k < 4; ++k) {
        int jk = j + k + hbase;
        int sj = __shfl(s, jk, 64);         // one ds_bpermute each
        float aj = __shfl(a, jk, 64);
        const __half2* hp = (const __half2*)(h2 + (size_t)sj * 64);
        float2 hf = __half22float2(hp[hl]);
        ox = fmaf(aj, hf.x, ox);
        oy = fmaf(aj, hf.y, oy);
      }
    }
  } else {
    float m = NEG_BIG, dsum = 0.f;
    for (int base = beg; base < end; base += 32) {
      int idx = base + hl;
      int s = (idx < end) ? csr[idx] : 0;
      s = ((unsigned)s < (unsigned)N) ? s : 0;
      float e = el[s] + ern;
      e = e > 0.f ? e : 0.2f * e;
      e = (idx < end) ? e : NEG_BIG;
      float mn = fmaxf(m, halfMax(e));
      dsum = dsum * __expf(m - mn) + halfSum(__expf(e - mn));
      m = mn;
    }
    float inv = (deg > 0) ? 1.f / dsum : 0.f;
    for (int base = beg; base < end; base += 32) {
      int idx = base + hl;
      int s = (idx < end) ? csr[idx] : 0;
      s = ((unsigned)s < (unsigned)N) ? s : 0;
      float e = el[s] + ern;
      e = e > 0.f ? e : 0.2f * e;
      float a = (idx < end) ? __expf(e - m) * inv : 0.f;
      for (int j = 0; j < 32; ++j) {
        int jk = j + hbase;
        int sj = __shfl(s, jk, 64);
        float aj = __shfl(a, jk, 64);
        const __half2* hp = (const __half2*)(h2 + (size_t)sj * 64);
        float2 hf = __half22float2(hp[hl]);
        ox = fmaf(aj, hf.x, ox);
        oy = fmaf(aj, hf.y, oy);
      }
    }
  }
  float2 bb = ((const float2*)b2)[hl];
  float r0 = ox + bb.x, r1 = oy + bb.y;
  r0 = r0 > 0.f ? r0 : 0.01f * r0;
  r1 = r1 > 0.f ? r1 : 0.01f * r1;
  int k0 = 2 * hl, k1 = 2 * hl + 1;
  float p0 = halfSum(fmaf(r0, W3[k0 * 3 + 0], r1 * W3[k1 * 3 + 0]));
  float p1 = halfSum(fmaf(r0, W3[k0 * 3 + 1], r1 * W3[k1 * 3 + 1]));
  float p2 = halfSum(fmaf(r0, W3[k0 * 3 + 2], r1 * W3[k1 * 3 + 2]));
  if (hl == 0 && pn < N) {
    float el3 = fmaf(p0, al3[0], fmaf(p1, al3[1], p2 * al3[2]));
    h3[n * 4 + 0] = p0; h3[n * 4 + 1] = p1; h3[n * 4 + 2] = p2; h3[n * 4 + 3] = el3;
  }
}

// ---------- final aggregate (2 nodes/wave), logits in h3.w ----------
__global__ __launch_bounds__(256) void k_agg3(
    const float4* __restrict__ h3, const int* __restrict__ start,
    const int* __restrict__ csr, const float* __restrict__ ar3,
    const float* __restrict__ b, float* __restrict__ out, int N) {
  int tid = threadIdx.x;
  int wave = tid >> 6, lane = tid & 63, hl = lane & 31, half = lane >> 5;
  int pn = blockIdx.x * 8 + wave * 2 + half;
  int n = (pn < N) ? pn : 0;
  int beg = start[n], end = start[n + 1];
  float4 hn = h3[n];
  float ern = fmaf(hn.x, ar3[0], fmaf(hn.y, ar3[1], hn.z * ar3[2]));
  float m = NEG_BIG, d = 0.f, Q0 = 0.f, Q1 = 0.f, Q2 = 0.f;
  for (int base = beg; base < end; base += 32) {
    int idx = base + hl;
    int s = (idx < end) ? ntI(&csr[idx]) : 0;
    s = ((unsigned)s < (unsigned)N) ? s : 0;
    float4 hv = h3[s];
    float e = hv.w + ern;
    e = e > 0.f ? e : 0.2f * e;
    e = (idx < end) ? e : NEG_BIG;
    float mn = fmaxf(m, halfMax(e));
    float sc = __expf(m - mn);
    float q = __expf(e - mn);
    d = d * sc + halfSum(q);
    Q0 = Q0 * sc + halfSum(q * hv.x);
    Q1 = Q1 * sc + halfSum(q * hv.y);
    Q2 = Q2 * sc + halfSum(q * hv.z);
    m = mn;
  }
  float inv = (end > beg) ? 1.f / d : 0.f;
  if (hl == 0 && pn < N) {
    out[n * 3 + 0] = fmaf(Q0, inv, b[0]);
    out[n * 3 + 1] = fmaf(Q1, inv, b[1]);
    out[n * 3 + 2] = fmaf(Q2, inv, b[2]);
  }
}

extern "C" void kernel_launch(void* const* d_in, const int* in_sizes, int n_in,
                              void* d_out, int out_size, void* d_ws, size_t ws_size,
                              hipStream_t stream) {
  const int N = in_sizes[0] / 3;
  const int E = in_sizes[1];
  const float* feats = (const float*)d_in[0];
  const int* src = (const int*)d_in[1];
  const int* dst = (const int*)d_in[2];
  const float* W1  = (const float*)d_in[3];
  const float* al1 = (const float*)d_in[4];
  const float* ar1 = (const float*)d_in[5];
  const float* b1  = (const float*)d_in[6];
  const float* W2  = (const float*)d_in[7];
  const float* al2 = (const float*)d_in[8];
  const float* ar2 = (const float*)d_in[9];
  const float* b2  = (const float*)d_in[10];
  const float* W3  = (const float*)d_in[11];
  const float* al3 = (const float*)d_in[12];
  const float* ar3 = (const float*)d_in[13];
  const float* b3  = (const float*)d_in[14];

  const int NBK = (N + 255) >> 8;       // 391 buckets of 256 dsts

  char* ws = (char*)d_ws;
  size_t off = 0;
  auto alloc = [&](size_t bytes) -> void* {
    void* p = ws + off;
    off = (off + bytes + 255) & ~(size_t)255;
    return p;
  };
  int* startv  = (int*)alloc((size_t)(N + 1) * 4);
  int* csr     = (int*)alloc((size_t)E * 4);
  float* elB   = (float*)alloc((size_t)N * 4);
  float* erB   = (float*)alloc((size_t)N * 4);
  float* er1   = (float*)alloc((size_t)N * 4);
  int* gcount  = (int*)alloc((size_t)NBK * 4);
  int* baseb   = (int*)alloc((size_t)(NBK + 1) * 4);
  int* cursorb = (int*)alloc((size_t)NBK * 4);
  float* uvw   = (float*)alloc(1024);
  float* h3    = (float*)alloc((size_t)N * 4 * 4);     // [N,4], w=el3
  float4* x4   = (float4*)alloc((size_t)N * 16);       // (x, u·x)
  __half* x2   = (__half*)alloc((size_t)N * 64 * 2);   // x2 -> h2 in-place
  unsigned* binned = (unsigned*)x2;                    // alias: dead pre-agg1x
  // total ~26 MB

  const int NB  = (N + 255) / 256;
  const int NB8 = (N + 7) / 8;
  const int GB  = (N + 63) / 64;
  const int CB  = (E + CHUNK - 1) / CHUNK;

  k_prep<<<1, 64, 0, stream>>>(W1, al1, ar1, W2, al2, ar2, uvw);
  k_padx<<<NB, 256, 0, stream>>>(feats, uvw, x4, er1, N);

  hipMemsetAsync(gcount, 0, (size_t)NBK * 4, stream);
  k_hist<<<CB, 256, 0, stream>>>(dst, gcount, E, NBK);
  k_bscan<<<1, 1024, 0, stream>>>(gcount, baseb, cursorb, NBK, E, startv, N);
  k_bin2<<<CB, 256, 0, stream>>>(src, dst, cursorb, binned, E, NBK);
  k_sort<<<NBK, 256, 0, stream>>>(binned, baseb, csr, startv, N);

  k_agg1x<<<NB8, 256, 0, stream>>>(x4, er1, uvw, W1, b1, startv, csr,
                                   x2, elB, erB, N);
  k_gemm2<<<GB, 256, 0, stream>>>(x2, W2, x2, N);   // in-place x2 -> h2
  k_agg2f<<<NB8, 256, 0, stream>>>(x2, elB, erB, startv, csr, b2, W3, al3, h3, N);
  k_agg3<<<NB8, 256, 0, stream>>>((const float4*)h3, startv, csr, ar3, b3,
                                  (float*)d_out, N);
}

// Round 14
// 271.644 us; speedup vs baseline: 1.0734x; 1.0734x over previous
//
#include <hip/hip_runtime.h>
#include <hip/hip_fp16.h>
#include <math.h>

// GAT 3-layer net, v14.
//  - v13 post-mortem: lane-varying __shfl (ds_bpermute) ballooned VGPR 20->48,
//    occupancy 66->43% -> REGRESSED. Reverted.
//  - v14: agg2f phase-B broadcast via LDS staging: phase A writes each
//    half-wave's (s,a) to a private 2KB LDS slice (1 ds_write_b64/lane,
//    once); phase B reads ds_read_b64 at half-uniform address (broadcast,
//    conflict-free). Deletes 4 readlane + 2 cndmask per edge-slot with NO
//    per-lane index state -> VGPR stays low. One unconditional
//    __syncthreads (no early returns exist). Generic deg>32 path = v12.
//  - Everything else identical to v12 (279us).

#define NEG_BIG (-1e30f)
#define SORT_CAP 6144
#define CHUNK 8192

__device__ inline float waveSum(float v) {
#pragma unroll
  for (int off = 32; off; off >>= 1) v += __shfl_xor(v, off, 64);
  return v;
}

__device__ inline float halfSum(float v) {
#pragma unroll
  for (int off = 16; off; off >>= 1) v += __shfl_xor(v, off, 64);
  return v;
}

__device__ inline float halfMax(float v) {
#pragma unroll
  for (int off = 16; off; off >>= 1) v = fmaxf(v, __shfl_xor(v, off, 64));
  return v;
}

__device__ inline int waveMaxI(int v) {
#pragma unroll
  for (int off = 32; off; off >>= 1) v = max(v, __shfl_xor(v, off, 64));
  return v;
}

__device__ inline int rlI(int v, int l) { return __builtin_amdgcn_readlane(v, l); }
__device__ inline float rlF(float v, int l) {
  return __int_as_float(__builtin_amdgcn_readlane(__float_as_int(v), l));
}
__device__ inline int ntI(const int* p) { return __builtin_nontemporal_load(p); }

// ---------- bucket binning: LDS-chunked histogram ----------
__global__ __launch_bounds__(256) void k_hist(const int* __restrict__ dst,
                                              int* __restrict__ gcount,
                                              int E, int NBK) {
  __shared__ int lcnt[512];
  int tid = threadIdx.x;
  for (int b = tid; b < NBK; b += 256) lcnt[b] = 0;
  __syncthreads();
  int e0 = blockIdx.x * CHUNK;
  int e1 = min(e0 + CHUNK, E);
  for (int e = e0 + tid; e < e1; e += 256)
    atomicAdd(&lcnt[ntI(&dst[e]) >> 8], 1);
  __syncthreads();
  for (int b = tid; b < NBK; b += 256)
    if (lcnt[b]) atomicAdd(&gcount[b], lcnt[b]);
}

// single block: exclusive scan of gcount[NBK] -> base, cursor
__global__ void k_bscan(const int* __restrict__ cnt, int* __restrict__ base,
                        int* __restrict__ cursor, int NBK, int E,
                        int* __restrict__ startv, int N) {
  __shared__ int s[1024];
  int t = threadIdx.x;
  int v = (t < NBK) ? cnt[t] : 0;
  s[t] = v;
  __syncthreads();
  for (int off = 1; off < 1024; off <<= 1) {
    int u = (t >= off) ? s[t - off] : 0;
    __syncthreads();
    s[t] += u;
    __syncthreads();
  }
  int excl = s[t] - v;
  if (t < NBK) { base[t] = excl; cursor[t] = excl; }
  if (t == NBK) base[t] = excl;         // == E
  if (t == 0) startv[N] = E;
}

// block-chunked bin: reserve contiguous ranges, write runs
__global__ __launch_bounds__(256) void k_bin2(
    const int* __restrict__ src, const int* __restrict__ dst,
    int* __restrict__ gcursor, unsigned* __restrict__ binned, int E, int NBK) {
  __shared__ int lcnt[512];
  __shared__ int lbase[512];
  int tid = threadIdx.x;
  for (int b = tid; b < NBK; b += 256) lcnt[b] = 0;
  __syncthreads();
  int e0 = blockIdx.x * CHUNK;
  int e1 = min(e0 + CHUNK, E);
  for (int e = e0 + tid; e < e1; e += 256)
    atomicAdd(&lcnt[ntI(&dst[e]) >> 8], 1);
  __syncthreads();
  for (int b = tid; b < NBK; b += 256) {
    int c = lcnt[b];
    lbase[b] = c ? atomicAdd(&gcursor[b], c) : 0;
    lcnt[b] = 0;
  }
  __syncthreads();
  for (int e = e0 + tid; e < e1; e += 256) {
    int dd = ntI(&dst[e]);
    int ss = ntI(&src[e]);
    int b = dd >> 8;
    int pos = lbase[b] + atomicAdd(&lcnt[b], 1);
    binned[pos] = ((unsigned)(dd & 255) << 24) | (unsigned)ss;
  }
}

// one block per bucket: per-dst order within bucket, coalesced csr write
__global__ __launch_bounds__(256) void k_sort(
    const unsigned* __restrict__ binned, const int* __restrict__ base,
    int* __restrict__ csr, int* __restrict__ startv, int N) {
  __shared__ unsigned sbuf[SORT_CAP];
  __shared__ unsigned obuf[SORT_CAP];
  __shared__ int hist[256];
  __shared__ int scn[256];
  __shared__ int cur[256];
  int b = blockIdx.x;
  int tid = threadIdx.x;
  int gbase = base[b];
  int gend = base[b + 1];
  int cnt = gend - gbase;
  hist[tid] = 0;
  __syncthreads();
  if (cnt <= SORT_CAP) {
    for (int i = tid; i < cnt; i += 256) {
      unsigned w = binned[gbase + i];
      sbuf[i] = w;
      atomicAdd(&hist[w >> 24], 1);
    }
    __syncthreads();
    int v = hist[tid];
    scn[tid] = v;
    __syncthreads();
    for (int off = 1; off < 256; off <<= 1) {
      int u = (tid >= off) ? scn[tid - off] : 0;
      __syncthreads();
      scn[tid] += u;
      __syncthreads();
    }
    int excl = scn[tid] - v;
    cur[tid] = excl;
    int dn = b * 256 + tid;
    if (dn < N) startv[dn] = gbase + excl;
    __syncthreads();
    for (int i = tid; i < cnt; i += 256) {
      unsigned w = sbuf[i];
      int p = atomicAdd(&cur[w >> 24], 1);
      obuf[p] = w & 0xFFFFFFu;
    }
    __syncthreads();
    for (int i = tid; i < cnt; i += 256) csr[gbase + i] = (int)obuf[i];
  } else {
    for (int i = tid; i < cnt; i += 256)
      atomicAdd(&hist[binned[gbase + i] >> 24], 1);
    __syncthreads();
    int v = hist[tid];
    scn[tid] = v;
    __syncthreads();
    for (int off = 1; off < 256; off <<= 1) {
      int u = (tid >= off) ? scn[tid - off] : 0;
      __syncthreads();
      scn[tid] += u;
      __syncthreads();
    }
    int excl = scn[tid] - v;
    cur[tid] = excl;
    int dn = b * 256 + tid;
    if (dn < N) startv[dn] = gbase + excl;
    __syncthreads();
    for (int i = tid; i < cnt; i += 256) {
      unsigned w = binned[gbase + i];
      int p = atomicAdd(&cur[w >> 24], 1);
      csr[gbase + p] = (int)(w & 0xFFFFFFu);
    }
  }
}

// ---------- prep: uvw[0..5]=W1@al1|W1@ar1; [8..71]=W2@al2; [72..135]=W2@ar2
__global__ void k_prep(const float* __restrict__ W1, const float* __restrict__ al1,
                       const float* __restrict__ ar1, const float* __restrict__ W2,
                       const float* __restrict__ al2, const float* __restrict__ ar2,
                       float* __restrict__ uvw) {
  int lane = threadIdx.x & 63;
  float a = al1[lane], r = ar1[lane];
#pragma unroll
  for (int i = 0; i < 3; ++i) {
    float w = W1[i * 64 + lane];
    float ui = waveSum(w * a);
    float vi = waveSum(w * r);
    if (lane == 0) { uvw[i] = ui; uvw[3 + i] = vi; }
  }
  float sa = 0.f, sr = 0.f;
  for (int j = 0; j < 64; ++j) {
    float w = W2[lane * 64 + j];
    sa = fmaf(w, al2[j], sa);
    sr = fmaf(w, ar2[j], sr);
  }
  uvw[8 + lane] = sa;
  uvw[72 + lane] = sr;
}

// ---------- pad x + per-node layer-1 logits: x4=(x, u·x), er1=v·x ----------
__global__ void k_padx(const float* __restrict__ x, const float* __restrict__ uvw,
                       float4* __restrict__ x4, float* __restrict__ er1, int N) {
  int n = blockIdx.x * blockDim.x + threadIdx.x;
  if (n >= N) return;
  float x0 = __builtin_nontemporal_load(&x[n * 3]);
  float x1 = __builtin_nontemporal_load(&x[n * 3 + 1]);
  float x2 = __builtin_nontemporal_load(&x[n * 3 + 2]);
  float el = fmaf(x0, uvw[0], fmaf(x1, uvw[1], x2 * uvw[2]));
  float er = fmaf(x0, uvw[3], fmaf(x1, uvw[4], x2 * uvw[5]));
  x4[n] = make_float4(x0, x1, x2, el);
  er1[n] = er;
}

// ---------- layer-1: x-space agg (2 nodes/wave) -> x2 fp16, el2/er2 --------
__global__ __launch_bounds__(256) void k_agg1x(
    const float4* __restrict__ x4, const float* __restrict__ er1,
    const float* __restrict__ uvw, const float* __restrict__ W1,
    const float* __restrict__ b1, const int* __restrict__ start,
    const int* __restrict__ csr, __half* __restrict__ x2,
    float* __restrict__ el2, float* __restrict__ er2, int N) {
  int tid = threadIdx.x;
  int wave = tid >> 6, lane = tid & 63, hl = lane & 31, half = lane >> 5;
  int pA = blockIdx.x * 8 + wave * 2;
  int pn = pA + half;
  int n = (pn < N) ? pn : 0;
  int beg = start[n], end = start[n + 1];
  float ern = er1[n];
  float m = NEG_BIG, d = 0.f, X0 = 0.f, X1 = 0.f, X2 = 0.f;
  for (int base = beg; base < end; base += 32) {
    int idx = base + hl;
    int s = (idx < end) ? ntI(&csr[idx]) : 0;
    s = ((unsigned)s < (unsigned)N) ? s : 0;
    float4 hv = x4[s];
    float e = hv.w + ern;
    e = e > 0.f ? e : 0.2f * e;             // attn leaky_relu(0.2)
    e = (idx < end) ? e : NEG_BIG;
    float mn = fmaxf(m, halfMax(e));
    float sc = __expf(m - mn);
    float q = __expf(e - mn);
    d = d * sc + halfSum(q);
    X0 = X0 * sc + halfSum(q * hv.x);
    X1 = X1 * sc + halfSum(q * hv.y);
    X2 = X2 * sc + halfSum(q * hv.z);
    m = mn;
  }
  float inv = (end > beg) ? 1.f / d : 0.f;
  X0 *= inv; X1 *= inv; X2 *= inv;
  float A0 = rlF(X0, 0), A1 = rlF(X1, 0), A2 = rlF(X2, 0);
  float B0 = rlF(X0, 32), B1 = rlF(X1, 32), B2 = rlF(X2, 32);
  float w1a = W1[lane], w1b = W1[64 + lane], w1c = W1[128 + lane];
  float bb = b1[lane];
  float wal = uvw[8 + lane], war = uvw[72 + lane];
  {
    float vA = fmaf(A0, w1a, fmaf(A1, w1b, fmaf(A2, w1c, bb)));
    vA = vA > 0.f ? vA : 0.01f * vA;        // leaky_relu(0.01)
    float eA = waveSum(vA * wal);
    float rA = waveSum(vA * war);
    if (pA < N) {
      x2[(size_t)pA * 64 + lane] = __float2half(vA);
      if (lane == 0) { el2[pA] = eA; er2[pA] = rA; }
    }
  }
  {
    int pB = pA + 1;
    float vB = fmaf(B0, w1a, fmaf(B1, w1b, fmaf(B2, w1c, bb)));
    vB = vB > 0.f ? vB : 0.01f * vB;
    float eB = waveSum(vB * wal);
    float rB = waveSum(vB * war);
    if (pB < N) {
      x2[(size_t)pB * 64 + lane] = __float2half(vB);
      if (lane == 0) { el2[pB] = eB; er2[pB] = rB; }
    }
  }
}

// ---------- batched GEMM: h2 = x2 @ W2, in-place ----------
__global__ __launch_bounds__(256) void k_gemm2(const __half* x2_in,
                                               const float* __restrict__ W2,
                                               __half* h2_out, int N) {
  __shared__ float sW[64 * 64];
  __shared__ float sX[64 * 64];
  int tid = threadIdx.x;
  for (int i = tid; i < 4096; i += 256) sW[i] = W2[i];
  const unsigned* xu = (const unsigned*)x2_in;
  size_t base = (size_t)blockIdx.x * 2048;
  size_t limit = (size_t)N * 32;
  for (int i = tid; i < 2048; i += 256) {
    size_t gi = base + i;
    unsigned u = (gi < limit) ? __builtin_nontemporal_load(&xu[gi]) : 0u;
    __half2 hh = *(__half2*)&u;
    float2 f = __half22float2(hh);
    sX[2 * i] = f.x;
    sX[2 * i + 1] = f.y;
  }
  __syncthreads();
  int wave = tid >> 6, f = tid & 63;
  int r0 = wave * 16;
  float acc[16];
#pragma unroll
  for (int i = 0; i < 16; ++i) acc[i] = 0.f;
  const float2* sX2 = (const float2*)sX;
  for (int k2 = 0; k2 < 32; ++k2) {
    float wv0 = sW[(2 * k2) * 64 + f];
    float wv1 = sW[(2 * k2 + 1) * 64 + f];
#pragma unroll
    for (int i = 0; i < 16; ++i) {
      float2 xv = sX2[(r0 + i) * 32 + k2];
      acc[i] = fmaf(xv.x, wv0, fmaf(xv.y, wv1, acc[i]));
    }
  }
  int rowbase = blockIdx.x * 64 + r0;
#pragma unroll
  for (int i = 0; i < 16; ++i) {
    int row = rowbase + i;
    if (row < N) h2_out[(size_t)row * 64 + f] = __float2half(acc[i]);
  }
}

// ---------- layer-2 aggregate (2 nodes/wave) + fused W3 -> h3 (w=el3) ------
// Phase-B broadcast via per-wave LDS staging of (s,a): no per-lane index
// state (v13's bpermute VGPR blowup), no readlane/cndmask chain (v12).
__global__ __launch_bounds__(256) void k_agg2f(
    const __half* __restrict__ h2, const float* __restrict__ el,
    const float* __restrict__ er, const int* __restrict__ start,
    const int* __restrict__ csr, const float* __restrict__ b2,
    const float* __restrict__ W3, const float* __restrict__ al3,
    float* __restrict__ h3, int N) {
  __shared__ int2 sSA[4][64];               // [wave][half*32+slot] = (s, a-bits)
  int tid = threadIdx.x;
  int wave = tid >> 6, lane = tid & 63, hl = lane & 31, half = lane >> 5;
  int pn = blockIdx.x * 8 + wave * 2 + half;
  int n = (pn < N) ? pn : 0;
  int beg = start[n], end = start[n + 1];
  int deg = end - beg;
  int maxd = __builtin_amdgcn_readfirstlane(waveMaxI(deg));
  float ern = er[n];
  float ox = 0.f, oy = 0.f;

  // phase A (all waves; generic waves store zeros)
  int sA = 0; float aA = 0.f;
  if (maxd <= 32) {
    int idx = beg + hl;
    int s = (idx < end) ? ntI(&csr[idx]) : 0;
    s = ((unsigned)s < (unsigned)N) ? s : 0;
    float e = el[s] + ern;
    e = e > 0.f ? e : 0.2f * e;
    e = (idx < end) ? e : NEG_BIG;
    float mm = halfMax(e);
    float q = __expf(e - mm);
    float dsum = halfSum(q);
    float inv = (deg > 0) ? 1.f / dsum : 0.f;
    sA = s; aA = q * inv;                   // 0 for invalid lanes
  }
  sSA[wave][half * 32 + hl] = make_int2(sA, __float_as_int(aA));
  __syncthreads();

  if (maxd <= 32) {
    const int2* sp = &sSA[wave][half * 32];
    for (int j = 0; j < maxd; j += 4) {
#pragma unroll
      for (int k = 0; k < 4; ++k) {
        int2 w = sp[j + k];                 // ds_read_b64, half-uniform addr
        int sj = w.x;
        float aj = __int_as_float(w.y);
        const __half2* hp = (const __half2*)(h2 + (size_t)sj * 64);
        float2 hf = __half22float2(hp[hl]);
        ox = fmaf(aj, hf.x, ox);
        oy = fmaf(aj, hf.y, oy);
      }
    }
  } else {
    // generic chunked two-pass (rare) — v12 readlane form
    float m = NEG_BIG, dsum = 0.f;
    for (int base = beg; base < end; base += 32) {
      int idx = base + hl;
      int s = (idx < end) ? csr[idx] : 0;
      s = ((unsigned)s < (unsigned)N) ? s : 0;
      float e = el[s] + ern;
      e = e > 0.f ? e : 0.2f * e;
      e = (idx < end) ? e : NEG_BIG;
      float mn = fmaxf(m, halfMax(e));
      dsum = dsum * __expf(m - mn) + halfSum(__expf(e - mn));
      m = mn;
    }
    float inv = (deg > 0) ? 1.f / dsum : 0.f;
    for (int base = beg; base < end; base += 32) {
      int idx = base + hl;
      int s = (idx < end) ? csr[idx] : 0;
      s = ((unsigned)s < (unsigned)N) ? s : 0;
      float e = el[s] + ern;
      e = e > 0.f ? e : 0.2f * e;
      float a = (idx < end) ? __expf(e - m) * inv : 0.f;
      for (int j = 0; j < 32; ++j) {
        int sAx = rlI(s, j), sBx = rlI(s, j + 32);
        float aAx = rlF(a, j), aBx = rlF(a, j + 32);
        int sj = half ? sBx : sAx;
        float aj = half ? aBx : aAx;
        const __half2* hp = (const __half2*)(h2 + (size_t)sj * 64);
        float2 hf = __half22float2(hp[hl]);
        ox = fmaf(aj, hf.x, ox);
        oy = fmaf(aj, hf.y, oy);
      }
    }
  }
  float2 bb = ((const float2*)b2)[hl];
  float r0 = ox + bb.x, r1 = oy + bb.y;
  r0 = r0 > 0.f ? r0 : 0.01f * r0;
  r1 = r1 > 0.f ? r1 : 0.01f * r1;
  int k0 = 2 * hl, k1 = 2 * hl + 1;
  float p0 = halfSum(fmaf(r0, W3[k0 * 3 + 0], r1 * W3[k1 * 3 + 0]));
  float p1 = halfSum(fmaf(r0, W3[k0 * 3 + 1], r1 * W3[k1 * 3 + 1]));
  float p2 = halfSum(fmaf(r0, W3[k0 * 3 + 2], r1 * W3[k1 * 3 + 2]));
  if (hl == 0 && pn < N) {
    float el3 = fmaf(p0, al3[0], fmaf(p1, al3[1], p2 * al3[2]));
    h3[n * 4 + 0] = p0; h3[n * 4 + 1] = p1; h3[n * 4 + 2] = p2; h3[n * 4 + 3] = el3;
  }
}

// ---------- final aggregate (2 nodes/wave), logits in h3.w ----------
__global__ __launch_bounds__(256) void k_agg3(
    const float4* __restrict__ h3, const int* __restrict__ start,
    const int* __restrict__ csr, const float* __restrict__ ar3,
    const float* __restrict__ b, float* __restrict__ out, int N) {
  int tid = threadIdx.x;
  int wave = tid >> 6, lane = tid & 63, hl = lane & 31, half = lane >> 5;
  int pn = blockIdx.x * 8 + wave * 2 + half;
  int n = (pn < N) ? pn : 0;
  int beg = start[n], end = start[n + 1];
  float4 hn = h3[n];
  float ern = fmaf(hn.x, ar3[0], fmaf(hn.y, ar3[1], hn.z * ar3[2]));
  float m = NEG_BIG, d = 0.f, Q0 = 0.f, Q1 = 0.f, Q2 = 0.f;
  for (int base = beg; base < end; base += 32) {
    int idx = base + hl;
    int s = (idx < end) ? ntI(&csr[idx]) : 0;
    s = ((unsigned)s < (unsigned)N) ? s : 0;
    float4 hv = h3[s];
    float e = hv.w + ern;
    e = e > 0.f ? e : 0.2f * e;
    e = (idx < end) ? e : NEG_BIG;
    float mn = fmaxf(m, halfMax(e));
    float sc = __expf(m - mn);
    float q = __expf(e - mn);
    d = d * sc + halfSum(q);
    Q0 = Q0 * sc + halfSum(q * hv.x);
    Q1 = Q1 * sc + halfSum(q * hv.y);
    Q2 = Q2 * sc + halfSum(q * hv.z);
    m = mn;
  }
  float inv = (end > beg) ? 1.f / d : 0.f;
  if (hl == 0 && pn < N) {
    out[n * 3 + 0] = fmaf(Q0, inv, b[0]);
    out[n * 3 + 1] = fmaf(Q1, inv, b[1]);
    out[n * 3 + 2] = fmaf(Q2, inv, b[2]);
  }
}

extern "C" void kernel_launch(void* const* d_in, const int* in_sizes, int n_in,
                              void* d_out, int out_size, void* d_ws, size_t ws_size,
                              hipStream_t stream) {
  const int N = in_sizes[0] / 3;
  const int E = in_sizes[1];
  const float* feats = (const float*)d_in[0];
  const int* src = (const int*)d_in[1];
  const int* dst = (const int*)d_in[2];
  const float* W1  = (const float*)d_in[3];
  const float* al1 = (const float*)d_in[4];
  const float* ar1 = (const float*)d_in[5];
  const float* b1  = (const float*)d_in[6];
  const float* W2  = (const float*)d_in[7];
  const float* al2 = (const float*)d_in[8];
  const float* ar2 = (const float*)d_in[9];
  const float* b2  = (const float*)d_in[10];
  const float* W3  = (const float*)d_in[11];
  const float* al3 = (const float*)d_in[12];
  const float* ar3 = (const float*)d_in[13];
  const float* b3  = (const float*)d_in[14];

  const int NBK = (N + 255) >> 8;       // 391 buckets of 256 dsts

  char* ws = (char*)d_ws;
  size_t off = 0;
  auto alloc = [&](size_t bytes) -> void* {
    void* p = ws + off;
    off = (off + bytes + 255) & ~(size_t)255;
    return p;
  };
  int* startv  = (int*)alloc((size_t)(N + 1) * 4);
  int* csr     = (int*)alloc((size_t)E * 4);
  float* elB   = (float*)alloc((size_t)N * 4);
  float* erB   = (float*)alloc((size_t)N * 4);
  float* er1   = (float*)alloc((size_t)N * 4);
  int* gcount  = (int*)alloc((size_t)NBK * 4);
  int* baseb   = (int*)alloc((size_t)(NBK + 1) * 4);
  int* cursorb = (int*)alloc((size_t)NBK * 4);
  float* uvw   = (float*)alloc(1024);
  float* h3    = (float*)alloc((size_t)N * 4 * 4);     // [N,4], w=el3
  float4* x4   = (float4*)alloc((size_t)N * 16);       // (x, u·x)
  __half* x2   = (__half*)alloc((size_t)N * 64 * 2);   // x2 -> h2 in-place
  unsigned* binned = (unsigned*)x2;                    // alias: dead pre-agg1x
  // total ~26 MB

  const int NB  = (N + 255) / 256;
  const int NB8 = (N + 7) / 8;
  const int GB  = (N + 63) / 64;
  const int CB  = (E + CHUNK - 1) / CHUNK;

  k_prep<<<1, 64, 0, stream>>>(W1, al1, ar1, W2, al2, ar2, uvw);
  k_padx<<<NB, 256, 0, stream>>>(feats, uvw, x4, er1, N);

  hipMemsetAsync(gcount, 0, (size_t)NBK * 4, stream);
  k_hist<<<CB, 256, 0, stream>>>(dst, gcount, E, NBK);
  k_bscan<<<1, 1024, 0, stream>>>(gcount, baseb, cursorb, NBK, E, startv, N);
  k_bin2<<<CB, 256, 0, stream>>>(src, dst, cursorb, binned, E, NBK);
  k_sort<<<NBK, 256, 0, stream>>>(binned, baseb, csr, startv, N);

  k_agg1x<<<NB8, 256, 0, stream>>>(x4, er1, uvw, W1, b1, startv, csr,
                                   x2, elB, erB, N);
  k_gemm2<<<GB, 256, 0, stream>>>(x2, W2, x2, N);   // in-place x2 -> h2
  k_agg2f<<<NB8, 256, 0, stream>>>(x2, elB, erB, startv, csr, b2, W3, al3, h3, N);
  k_agg3<<<NB8, 256, 0, stream>>>((const float4*)h3, startv, csr, ar3, b3,
                                  (float*)d_out, N);
}

// Round 15
// 268.432 us; speedup vs baseline: 1.0862x; 1.0120x over previous
//
#include <hip/hip_runtime.h>
#include <hip/hip_fp16.h>
#include <math.h>

// GAT 3-layer net, v15.
//  - v14 (272us): LDS-staged agg2f phase-B confirmed. Profile now flat;
//    top own-kernel ~48us. Harness ws-poison fill (47us) untouchable.
//  - v15: agg1x epilogue reductions deleted -- el2/er2 (= x2·(W2@al2),
//    x2·(W2@ar2)) now computed inside k_gemm2 from its staged sX tile
//    (threads 0..63: serial 64-FMA dot/row, hidden under the 1024-FMA/thread
//    GEMM loop). agg1x loses 4 waveSums (24 shfl) + wal/war loads per wave.
//  - Everything else identical to v14.

#define NEG_BIG (-1e30f)
#define SORT_CAP 6144
#define CHUNK 8192

__device__ inline float waveSum(float v) {
#pragma unroll
  for (int off = 32; off; off >>= 1) v += __shfl_xor(v, off, 64);
  return v;
}

__device__ inline float halfSum(float v) {
#pragma unroll
  for (int off = 16; off; off >>= 1) v += __shfl_xor(v, off, 64);
  return v;
}

__device__ inline float halfMax(float v) {
#pragma unroll
  for (int off = 16; off; off >>= 1) v = fmaxf(v, __shfl_xor(v, off, 64));
  return v;
}

__device__ inline int waveMaxI(int v) {
#pragma unroll
  for (int off = 32; off; off >>= 1) v = max(v, __shfl_xor(v, off, 64));
  return v;
}

__device__ inline int rlI(int v, int l) { return __builtin_amdgcn_readlane(v, l); }
__device__ inline float rlF(float v, int l) {
  return __int_as_float(__builtin_amdgcn_readlane(__float_as_int(v), l));
}
__device__ inline int ntI(const int* p) { return __builtin_nontemporal_load(p); }

// ---------- bucket binning: LDS-chunked histogram ----------
__global__ __launch_bounds__(256) void k_hist(const int* __restrict__ dst,
                                              int* __restrict__ gcount,
                                              int E, int NBK) {
  __shared__ int lcnt[512];
  int tid = threadIdx.x;
  for (int b = tid; b < NBK; b += 256) lcnt[b] = 0;
  __syncthreads();
  int e0 = blockIdx.x * CHUNK;
  int e1 = min(e0 + CHUNK, E);
  for (int e = e0 + tid; e < e1; e += 256)
    atomicAdd(&lcnt[ntI(&dst[e]) >> 8], 1);
  __syncthreads();
  for (int b = tid; b < NBK; b += 256)
    if (lcnt[b]) atomicAdd(&gcount[b], lcnt[b]);
}

// single block: exclusive scan of gcount[NBK] -> base, cursor
__global__ void k_bscan(const int* __restrict__ cnt, int* __restrict__ base,
                        int* __restrict__ cursor, int NBK, int E,
                        int* __restrict__ startv, int N) {
  __shared__ int s[1024];
  int t = threadIdx.x;
  int v = (t < NBK) ? cnt[t] : 0;
  s[t] = v;
  __syncthreads();
  for (int off = 1; off < 1024; off <<= 1) {
    int u = (t >= off) ? s[t - off] : 0;
    __syncthreads();
    s[t] += u;
    __syncthreads();
  }
  int excl = s[t] - v;
  if (t < NBK) { base[t] = excl; cursor[t] = excl; }
  if (t == NBK) base[t] = excl;         // == E
  if (t == 0) startv[N] = E;
}

// block-chunked bin: reserve contiguous ranges, write runs
__global__ __launch_bounds__(256) void k_bin2(
    const int* __restrict__ src, const int* __restrict__ dst,
    int* __restrict__ gcursor, unsigned* __restrict__ binned, int E, int NBK) {
  __shared__ int lcnt[512];
  __shared__ int lbase[512];
  int tid = threadIdx.x;
  for (int b = tid; b < NBK; b += 256) lcnt[b] = 0;
  __syncthreads();
  int e0 = blockIdx.x * CHUNK;
  int e1 = min(e0 + CHUNK, E);
  for (int e = e0 + tid; e < e1; e += 256)
    atomicAdd(&lcnt[ntI(&dst[e]) >> 8], 1);
  __syncthreads();
  for (int b = tid; b < NBK; b += 256) {
    int c = lcnt[b];
    lbase[b] = c ? atomicAdd(&gcursor[b], c) : 0;
    lcnt[b] = 0;
  }
  __syncthreads();
  for (int e = e0 + tid; e < e1; e += 256) {
    int dd = ntI(&dst[e]);
    int ss = ntI(&src[e]);
    int b = dd >> 8;
    int pos = lbase[b] + atomicAdd(&lcnt[b], 1);
    binned[pos] = ((unsigned)(dd & 255) << 24) | (unsigned)ss;
  }
}

// one block per bucket: per-dst order within bucket, coalesced csr write
__global__ __launch_bounds__(256) void k_sort(
    const unsigned* __restrict__ binned, const int* __restrict__ base,
    int* __restrict__ csr, int* __restrict__ startv, int N) {
  __shared__ unsigned sbuf[SORT_CAP];
  __shared__ unsigned obuf[SORT_CAP];
  __shared__ int hist[256];
  __shared__ int scn[256];
  __shared__ int cur[256];
  int b = blockIdx.x;
  int tid = threadIdx.x;
  int gbase = base[b];
  int gend = base[b + 1];
  int cnt = gend - gbase;
  hist[tid] = 0;
  __syncthreads();
  if (cnt <= SORT_CAP) {
    for (int i = tid; i < cnt; i += 256) {
      unsigned w = binned[gbase + i];
      sbuf[i] = w;
      atomicAdd(&hist[w >> 24], 1);
    }
    __syncthreads();
    int v = hist[tid];
    scn[tid] = v;
    __syncthreads();
    for (int off = 1; off < 256; off <<= 1) {
      int u = (tid >= off) ? scn[tid - off] : 0;
      __syncthreads();
      scn[tid] += u;
      __syncthreads();
    }
    int excl = scn[tid] - v;
    cur[tid] = excl;
    int dn = b * 256 + tid;
    if (dn < N) startv[dn] = gbase + excl;
    __syncthreads();
    for (int i = tid; i < cnt; i += 256) {
      unsigned w = sbuf[i];
      int p = atomicAdd(&cur[w >> 24], 1);
      obuf[p] = w & 0xFFFFFFu;
    }
    __syncthreads();
    for (int i = tid; i < cnt; i += 256) csr[gbase + i] = (int)obuf[i];
  } else {
    for (int i = tid; i < cnt; i += 256)
      atomicAdd(&hist[binned[gbase + i] >> 24], 1);
    __syncthreads();
    int v = hist[tid];
    scn[tid] = v;
    __syncthreads();
    for (int off = 1; off < 256; off <<= 1) {
      int u = (tid >= off) ? scn[tid - off] : 0;
      __syncthreads();
      scn[tid] += u;
      __syncthreads();
    }
    int excl = scn[tid] - v;
    cur[tid] = excl;
    int dn = b * 256 + tid;
    if (dn < N) startv[dn] = gbase + excl;
    __syncthreads();
    for (int i = tid; i < cnt; i += 256) {
      unsigned w = binned[gbase + i];
      int p = atomicAdd(&cur[w >> 24], 1);
      csr[gbase + p] = (int)(w & 0xFFFFFFu);
    }
  }
}

// ---------- prep: uvw[0..5]=W1@al1|W1@ar1; [8..71]=W2@al2; [72..135]=W2@ar2
__global__ void k_prep(const float* __restrict__ W1, const float* __restrict__ al1,
                       const float* __restrict__ ar1, const float* __restrict__ W2,
                       const float* __restrict__ al2, const float* __restrict__ ar2,
                       float* __restrict__ uvw) {
  int lane = threadIdx.x & 63;
  float a = al1[lane], r = ar1[lane];
#pragma unroll
  for (int i = 0; i < 3; ++i) {
    float w = W1[i * 64 + lane];
    float ui = waveSum(w * a);
    float vi = waveSum(w * r);
    if (lane == 0) { uvw[i] = ui; uvw[3 + i] = vi; }
  }
  float sa = 0.f, sr = 0.f;
  for (int j = 0; j < 64; ++j) {
    float w = W2[lane * 64 + j];
    sa = fmaf(w, al2[j], sa);
    sr = fmaf(w, ar2[j], sr);
  }
  uvw[8 + lane] = sa;
  uvw[72 + lane] = sr;
}

// ---------- pad x + per-node layer-1 logits: x4=(x, u·x), er1=v·x ----------
__global__ void k_padx(const float* __restrict__ x, const float* __restrict__ uvw,
                       float4* __restrict__ x4, float* __restrict__ er1, int N) {
  int n = blockIdx.x * blockDim.x + threadIdx.x;
  if (n >= N) return;
  float x0 = __builtin_nontemporal_load(&x[n * 3]);
  float x1 = __builtin_nontemporal_load(&x[n * 3 + 1]);
  float x2 = __builtin_nontemporal_load(&x[n * 3 + 2]);
  float el = fmaf(x0, uvw[0], fmaf(x1, uvw[1], x2 * uvw[2]));
  float er = fmaf(x0, uvw[3], fmaf(x1, uvw[4], x2 * uvw[5]));
  x4[n] = make_float4(x0, x1, x2, el);
  er1[n] = er;
}

// ---------- layer-1: x-space agg (2 nodes/wave) -> x2 fp16 ----------
// el2/er2 moved to k_gemm2 (v15): no reductions in the epilogue.
__global__ __launch_bounds__(256) void k_agg1x(
    const float4* __restrict__ x4, const float* __restrict__ er1,
    const float* __restrict__ W1, const float* __restrict__ b1,
    const int* __restrict__ start, const int* __restrict__ csr,
    __half* __restrict__ x2, int N) {
  int tid = threadIdx.x;
  int wave = tid >> 6, lane = tid & 63, hl = lane & 31, half = lane >> 5;
  int pA = blockIdx.x * 8 + wave * 2;
  int pn = pA + half;
  int n = (pn < N) ? pn : 0;
  int beg = start[n], end = start[n + 1];
  float ern = er1[n];
  float m = NEG_BIG, d = 0.f, X0 = 0.f, X1 = 0.f, X2 = 0.f;
  for (int base = beg; base < end; base += 32) {
    int idx = base + hl;
    int s = (idx < end) ? ntI(&csr[idx]) : 0;
    s = ((unsigned)s < (unsigned)N) ? s : 0;
    float4 hv = x4[s];
    float e = hv.w + ern;
    e = e > 0.f ? e : 0.2f * e;             // attn leaky_relu(0.2)
    e = (idx < end) ? e : NEG_BIG;
    float mn = fmaxf(m, halfMax(e));
    float sc = __expf(m - mn);
    float q = __expf(e - mn);
    d = d * sc + halfSum(q);
    X0 = X0 * sc + halfSum(q * hv.x);
    X1 = X1 * sc + halfSum(q * hv.y);
    X2 = X2 * sc + halfSum(q * hv.z);
    m = mn;
  }
  float inv = (end > beg) ? 1.f / d : 0.f;
  X0 *= inv; X1 *= inv; X2 *= inv;
  float A0 = rlF(X0, 0), A1 = rlF(X1, 0), A2 = rlF(X2, 0);
  float B0 = rlF(X0, 32), B1 = rlF(X1, 32), B2 = rlF(X2, 32);
  float w1a = W1[lane], w1b = W1[64 + lane], w1c = W1[128 + lane];
  float bb = b1[lane];
  if (pA < N) {
    float vA = fmaf(A0, w1a, fmaf(A1, w1b, fmaf(A2, w1c, bb)));
    vA = vA > 0.f ? vA : 0.01f * vA;        // leaky_relu(0.01)
    x2[(size_t)pA * 64 + lane] = __float2half(vA);
  }
  int pB = pA + 1;
  if (pB < N) {
    float vB = fmaf(B0, w1a, fmaf(B1, w1b, fmaf(B2, w1c, bb)));
    vB = vB > 0.f ? vB : 0.01f * vB;
    x2[(size_t)pB * 64 + lane] = __float2half(vB);
  }
}

// ---------- batched GEMM: h2 = x2 @ W2 in-place + el2/er2 from sX tile -----
__global__ __launch_bounds__(256) void k_gemm2(const __half* x2_in,
                                               const float* __restrict__ W2,
                                               const float* __restrict__ uvw,
                                               __half* h2_out,
                                               float* __restrict__ el2,
                                               float* __restrict__ er2, int N) {
  __shared__ float sW[64 * 64];
  __shared__ float sX[64 * 64];
  __shared__ float swal[64];
  __shared__ float swar[64];
  int tid = threadIdx.x;
  for (int i = tid; i < 4096; i += 256) sW[i] = W2[i];
  if (tid < 64) swal[tid] = uvw[8 + tid];
  else if (tid < 128) swar[tid - 64] = uvw[72 + tid - 64];
  const unsigned* xu = (const unsigned*)x2_in;
  size_t base = (size_t)blockIdx.x * 2048;
  size_t limit = (size_t)N * 32;
  for (int i = tid; i < 2048; i += 256) {
    size_t gi = base + i;
    unsigned u = (gi < limit) ? __builtin_nontemporal_load(&xu[gi]) : 0u;
    __half2 hh = *(__half2*)&u;
    float2 f = __half22float2(hh);
    sX[2 * i] = f.x;
    sX[2 * i + 1] = f.y;
  }
  __syncthreads();
  int wave = tid >> 6, f = tid & 63;
  int r0 = wave * 16;
  float acc[16];
#pragma unroll
  for (int i = 0; i < 16; ++i) acc[i] = 0.f;
  const float2* sX2 = (const float2*)sX;
  for (int k2 = 0; k2 < 32; ++k2) {
    float wv0 = sW[(2 * k2) * 64 + f];
    float wv1 = sW[(2 * k2 + 1) * 64 + f];
#pragma unroll
    for (int i = 0; i < 16; ++i) {
      float2 xv = sX2[(r0 + i) * 32 + k2];
      acc[i] = fmaf(xv.x, wv0, fmaf(xv.y, wv1, acc[i]));
    }
  }
  // el2/er2 dot products from the staged x2 tile (threads 0..63, one row each)
  if (tid < 64) {
    float sa = 0.f, sr = 0.f;
#pragma unroll 8
    for (int k = 0; k < 64; ++k) {
      float xv = sX[tid * 64 + k];
      sa = fmaf(xv, swal[k], sa);
      sr = fmaf(xv, swar[k], sr);
    }
    int row = blockIdx.x * 64 + tid;
    if (row < N) { el2[row] = sa; er2[row] = sr; }
  }
  int rowbase = blockIdx.x * 64 + r0;
#pragma unroll
  for (int i = 0; i < 16; ++i) {
    int row = rowbase + i;
    if (row < N) h2_out[(size_t)row * 64 + f] = __float2half(acc[i]);
  }
}

// ---------- layer-2 aggregate (2 nodes/wave) + fused W3 -> h3 (w=el3) ------
// Phase-B broadcast via per-wave LDS staging of (s,a).
__global__ __launch_bounds__(256) void k_agg2f(
    const __half* __restrict__ h2, const float* __restrict__ el,
    const float* __restrict__ er, const int* __restrict__ start,
    const int* __restrict__ csr, const float* __restrict__ b2,
    const float* __restrict__ W3, const float* __restrict__ al3,
    float* __restrict__ h3, int N) {
  __shared__ int2 sSA[4][64];               // [wave][half*32+slot] = (s, a-bits)
  int tid = threadIdx.x;
  int wave = tid >> 6, lane = tid & 63, hl = lane & 31, half = lane >> 5;
  int pn = blockIdx.x * 8 + wave * 2 + half;
  int n = (pn < N) ? pn : 0;
  int beg = start[n], end = start[n + 1];
  int deg = end - beg;
  int maxd = __builtin_amdgcn_readfirstlane(waveMaxI(deg));
  float ern = er[n];
  float ox = 0.f, oy = 0.f;

  int sA = 0; float aA = 0.f;
  if (maxd <= 32) {
    int idx = beg + hl;
    int s = (idx < end) ? ntI(&csr[idx]) : 0;
    s = ((unsigned)s < (unsigned)N) ? s : 0;
    float e = el[s] + ern;
    e = e > 0.f ? e : 0.2f * e;
    e = (idx < end) ? e : NEG_BIG;
    float mm = halfMax(e);
    float q = __expf(e - mm);
    float dsum = halfSum(q);
    float inv = (deg > 0) ? 1.f / dsum : 0.f;
    sA = s; aA = q * inv;                   // 0 for invalid lanes
  }
  sSA[wave][half * 32 + hl] = make_int2(sA, __float_as_int(aA));
  __syncthreads();

  if (maxd <= 32) {
    const int2* sp = &sSA[wave][half * 32];
    for (int j = 0; j < maxd; j += 4) {
#pragma unroll
      for (int k = 0; k < 4; ++k) {
        int2 w = sp[j + k];                 // ds_read_b64, half-uniform addr
        int sj = w.x;
        float aj = __int_as_float(w.y);
        const __half2* hp = (const __half2*)(h2 + (size_t)sj * 64);
        float2 hf = __half22float2(hp[hl]);
        ox = fmaf(aj, hf.x, ox);
        oy = fmaf(aj, hf.y, oy);
      }
    }
  } else {
    // generic chunked two-pass (rare) — readlane form
    float m = NEG_BIG, dsum = 0.f;
    for (int base = beg; base < end; base += 32) {
      int idx = base + hl;
      int s = (idx < end) ? csr[idx] : 0;
      s = ((unsigned)s < (unsigned)N) ? s : 0;
      float e = el[s] + ern;
      e = e > 0.f ? e : 0.2f * e;
      e = (idx < end) ? e : NEG_BIG;
      float mn = fmaxf(m, halfMax(e));
      dsum = dsum * __expf(m - mn) + halfSum(__expf(e - mn));
      m = mn;
    }
    float inv = (deg > 0) ? 1.f / dsum : 0.f;
    for (int base = beg; base < end; base += 32) {
      int idx = base + hl;
      int s = (idx < end) ? csr[idx] : 0;
      s = ((unsigned)s < (unsigned)N) ? s : 0;
      float e = el[s] + ern;
      e = e > 0.f ? e : 0.2f * e;
      float a = (idx < end) ? __expf(e - m) * inv : 0.f;
      for (int j = 0; j < 32; ++j) {
        int sAx = rlI(s, j), sBx = rlI(s, j + 32);
        float aAx = rlF(a, j), aBx = rlF(a, j + 32);
        int sj = half ? sBx : sAx;
        float aj = half ? aBx : aAx;
        const __half2* hp = (const __half2*)(h2 + (size_t)sj * 64);
        float2 hf = __half22float2(hp[hl]);
        ox = fmaf(aj, hf.x, ox);
        oy = fmaf(aj, hf.y, oy);
      }
    }
  }
  float2 bb = ((const float2*)b2)[hl];
  float r0 = ox + bb.x, r1 = oy + bb.y;
  r0 = r0 > 0.f ? r0 : 0.01f * r0;
  r1 = r1 > 0.f ? r1 : 0.01f * r1;
  int k0 = 2 * hl, k1 = 2 * hl + 1;
  float p0 = halfSum(fmaf(r0, W3[k0 * 3 + 0], r1 * W3[k1 * 3 + 0]));
  float p1 = halfSum(fmaf(r0, W3[k0 * 3 + 1], r1 * W3[k1 * 3 + 1]));
  float p2 = halfSum(fmaf(r0, W3[k0 * 3 + 2], r1 * W3[k1 * 3 + 2]));
  if (hl == 0 && pn < N) {
    float el3 = fmaf(p0, al3[0], fmaf(p1, al3[1], p2 * al3[2]));
    h3[n * 4 + 0] = p0; h3[n * 4 + 1] = p1; h3[n * 4 + 2] = p2; h3[n * 4 + 3] = el3;
  }
}

// ---------- final aggregate (2 nodes/wave), logits in h3.w ----------
__global__ __launch_bounds__(256) void k_agg3(
    const float4* __restrict__ h3, const int* __restrict__ start,
    const int* __restrict__ csr, const float* __restrict__ ar3,
    const float* __restrict__ b, float* __restrict__ out, int N) {
  int tid = threadIdx.x;
  int wave = tid >> 6, lane = tid & 63, hl = lane & 31, half = lane >> 5;
  int pn = blockIdx.x * 8 + wave * 2 + half;
  int n = (pn < N) ? pn : 0;
  int beg = start[n], end = start[n + 1];
  float4 hn = h3[n];
  float ern = fmaf(hn.x, ar3[0], fmaf(hn.y, ar3[1], hn.z * ar3[2]));
  float m = NEG_BIG, d = 0.f, Q0 = 0.f, Q1 = 0.f, Q2 = 0.f;
  for (int base = beg; base < end; base += 32) {
    int idx = base + hl;
    int s = (idx < end) ? ntI(&csr[idx]) : 0;
    s = ((unsigned)s < (unsigned)N) ? s : 0;
    float4 hv = h3[s];
    float e = hv.w + ern;
    e = e > 0.f ? e : 0.2f * e;
    e = (idx < end) ? e : NEG_BIG;
    float mn = fmaxf(m, halfMax(e));
    float sc = __expf(m - mn);
    float q = __expf(e - mn);
    d = d * sc + halfSum(q);
    Q0 = Q0 * sc + halfSum(q * hv.x);
    Q1 = Q1 * sc + halfSum(q * hv.y);
    Q2 = Q2 * sc + halfSum(q * hv.z);
    m = mn;
  }
  float inv = (end > beg) ? 1.f / d : 0.f;
  if (hl == 0 && pn < N) {
    out[n * 3 + 0] = fmaf(Q0, inv, b[0]);
    out[n * 3 + 1] = fmaf(Q1, inv, b[1]);
    out[n * 3 + 2] = fmaf(Q2, inv, b[2]);
  }
}

extern "C" void kernel_launch(void* const* d_in, const int* in_sizes, int n_in,
                              void* d_out, int out_size, void* d_ws, size_t ws_size,
                              hipStream_t stream) {
  const int N = in_sizes[0] / 3;
  const int E = in_sizes[1];
  const float* feats = (const float*)d_in[0];
  const int* src = (const int*)d_in[1];
  const int* dst = (const int*)d_in[2];
  const float* W1  = (const float*)d_in[3];
  const float* al1 = (const float*)d_in[4];
  const float* ar1 = (const float*)d_in[5];
  const float* b1  = (const float*)d_in[6];
  const float* W2  = (const float*)d_in[7];
  const float* al2 = (const float*)d_in[8];
  const float* ar2 = (const float*)d_in[9];
  const float* b2  = (const float*)d_in[10];
  const float* W3  = (const float*)d_in[11];
  const float* al3 = (const float*)d_in[12];
  const float* ar3 = (const float*)d_in[13];
  const float* b3  = (const float*)d_in[14];

  const int NBK = (N + 255) >> 8;       // 391 buckets of 256 dsts

  char* ws = (char*)d_ws;
  size_t off = 0;
  auto alloc = [&](size_t bytes) -> void* {
    void* p = ws + off;
    off = (off + bytes + 255) & ~(size_t)255;
    return p;
  };
  int* startv  = (int*)alloc((size_t)(N + 1) * 4);
  int* csr     = (int*)alloc((size_t)E * 4);
  float* elB   = (float*)alloc((size_t)N * 4);
  float* erB   = (float*)alloc((size_t)N * 4);
  float* er1   = (float*)alloc((size_t)N * 4);
  int* gcount  = (int*)alloc((size_t)NBK * 4);
  int* baseb   = (int*)alloc((size_t)(NBK + 1) * 4);
  int* cursorb = (int*)alloc((size_t)NBK * 4);
  float* uvw   = (float*)alloc(1024);
  float* h3    = (float*)alloc((size_t)N * 4 * 4);     // [N,4], w=el3
  float4* x4   = (float4*)alloc((size_t)N * 16);       // (x, u·x)
  __half* x2   = (__half*)alloc((size_t)N * 64 * 2);   // x2 -> h2 in-place
  unsigned* binned = (unsigned*)x2;                    // alias: dead pre-agg1x
  // total ~26 MB

  const int NB  = (N + 255) / 256;
  const int NB8 = (N + 7) / 8;
  const int GB  = (N + 63) / 64;
  const int CB  = (E + CHUNK - 1) / CHUNK;

  k_prep<<<1, 64, 0, stream>>>(W1, al1, ar1, W2, al2, ar2, uvw);
  k_padx<<<NB, 256, 0, stream>>>(feats, uvw, x4, er1, N);

  hipMemsetAsync(gcount, 0, (size_t)NBK * 4, stream);
  k_hist<<<CB, 256, 0, stream>>>(dst, gcount, E, NBK);
  k_bscan<<<1, 1024, 0, stream>>>(gcount, baseb, cursorb, NBK, E, startv, N);
  k_bin2<<<CB, 256, 0, stream>>>(src, dst, cursorb, binned, E, NBK);
  k_sort<<<NBK, 256, 0, stream>>>(binned, baseb, csr, startv, N);

  k_agg1x<<<NB8, 256, 0, stream>>>(x4, er1, W1, b1, startv, csr, x2, N);
  k_gemm2<<<GB, 256, 0, stream>>>(x2, W2, uvw, x2, elB, erB, N);  // in-place
  k_agg2f<<<NB8, 256, 0, stream>>>(x2, elB, erB, startv, csr, b2, W3, al3, h3, N);
  k_agg3<<<NB8, 256, 0, stream>>>((const float4*)h3, startv, csr, ar3, b3,
                                  (float*)d_out, N);
}